// Round 8
// baseline (794.188 us; speedup 1.0000x reference)
//
#include <hip/hip_runtime.h>
#include <hip/hip_bf16.h>

typedef unsigned short u16;
typedef unsigned int u32;
typedef unsigned long long u64;
typedef __attribute__((ext_vector_type(8))) short short8;
typedef __attribute__((ext_vector_type(4))) float f32x4;

#define NB 32      // trees
#define NN 128     // nodes per tree
#define HH 300     // hidden
#define G4 1200    // 4*H
#define NV 32000   // vocab
#define INW 350    // RD+E
#define KP 320     // padded K for MFMA; hb16 row stride

// scan decomposition
#define NSLICE 10   // 10 slices x 30 units
#define UPS 30      // hidden units per slice -> 120 gate rows
#define NREP 20     // chunk ch owned by rep ch%NREP
#define TPB 512     // 120 rows x 4 col-chunks = 480 active MV lanes
#define NROW 120
#define GMAX 16     // max node batch
#define NCHUNK 256  // 4096/16
#define MAXOWN 208  // 13 chunks x 16
#define PRW 484     // padded pr row stride

#define A_LD(p)     __hip_atomic_load((p), __ATOMIC_RELAXED, __HIP_MEMORY_SCOPE_AGENT)
#define A_ST(p, v)  __hip_atomic_store((p), (v), __ATOMIC_RELAXED, __HIP_MEMORY_SCOPE_AGENT)
#define A_ADD(p, v) __hip_atomic_fetch_add((p), (v), __ATOMIC_RELAXED, __HIP_MEMORY_SCOPE_AGENT)

__device__ __forceinline__ float sigm(float x) { return 1.f / (1.f + __expf(-x)); }
__device__ __forceinline__ float tanh_f(float x) {
    float e = __expf(2.f * x);
    return 1.f - 2.f / (e + 1.f);
}
__device__ __forceinline__ float bf2f(u16 v) {
    u32 u = ((u32)v) << 16;
    return __uint_as_float(u);
}
__device__ __forceinline__ u16 f2bf(float f) {
    __hip_bfloat16 b = __float2bfloat16(f);
    return *reinterpret_cast<u16*>(&b);
}

// hb16: [B][129][320] bf16 (slot 0 = root h); c_buf: [B][129][300] f32; done zeroed
__global__ void k_init(const float* __restrict__ rh, u16* __restrict__ hb16,
                       float* __restrict__ c_buf, int* __restrict__ done) {
    const int stride = gridDim.x * blockDim.x;
    const int idx = blockIdx.x * blockDim.x + threadIdx.x;
    for (int e = idx; e < NB * 129 * 20; e += stride) {
        int row = e / 20, c = 300 + (e - row * 20);
        hb16[(size_t)row * KP + c] = 0;
    }
    for (int e = idx; e < NB * HH; e += stride) {
        int b = e / HH, u = e - b * HH;
        float v = rh[e];
        hb16[(size_t)(b * 129) * KP + u] = f2bf(v);
        c_buf[(size_t)(b * 129) * HH + u] = v;
    }
    for (int e = idx; e < NB * NN; e += stride) done[e] = 0;
}

// WihT [350][1200]; Wpack[slice][i<75][t<480] = W_hh[row(s,t)][(t/120)*75+i]
// row(s,t) = 300*(rl/30) + 30*s + rl%30, rl = t%120
__global__ void k_pack(const float* __restrict__ W_ih, const float* __restrict__ W_hh,
                       float* __restrict__ WihT, float* __restrict__ Wpack) {
    const int tot = INW * G4 + NSLICE * 75 * 480;
    for (int n = blockIdx.x * blockDim.x + threadIdx.x; n < tot; n += gridDim.x * blockDim.x) {
        if (n < INW * G4) {
            int c = n / G4, r = n - c * G4;
            WihT[n] = W_ih[r * INW + c];
        } else {
            int m = n - INW * G4;
            int s = m / (75 * 480);
            int rem = m - s * (75 * 480);
            int i = rem / 480, t = rem - i * 480;
            int rl = t % NROW, cc = t / NROW;
            int row = 300 * (rl / UPS) + UPS * s + (rl % UPS);
            int col = cc * 75 + i;
            Wpack[m] = W_hh[row * HH + col];
        }
    }
}

// xg[node][1200] = concat(rel_emb[rel], emb[word]) @ W_ih^T + b_ih
__global__ __launch_bounds__(256) void k_xg(const int* __restrict__ relations,
                                            const int* __restrict__ prev_words,
                                            const float* __restrict__ rel_emb,
                                            const float* __restrict__ emb,
                                            const float* __restrict__ WihT,
                                            const float* __restrict__ b_ih,
                                            float* __restrict__ xg) {
    __shared__ float xl[8][INW];
    __shared__ int rid[8], wid[8];
    const int tid = threadIdx.x;
    const int nb = blockIdx.x * 8;
    if (tid < 8) { rid[tid] = relations[nb + tid]; wid[tid] = prev_words[nb + tid]; }
    __syncthreads();
    for (int idx = tid; idx < 8 * INW; idx += 256) {
        int g = idx / INW, c = idx - g * INW;
        xl[g][c] = (c < 50) ? rel_emb[rid[g] * 50 + c] : emb[wid[g] * HH + (c - 50)];
    }
    __syncthreads();
    for (int k = 0; k < 5; ++k) {
        int r = k * 256 + tid;
        if (r >= G4) break;
        float acc[8] = {0.f, 0.f, 0.f, 0.f, 0.f, 0.f, 0.f, 0.f};
        for (int c = 0; c < INW; ++c) {
            float wv = WihT[(size_t)c * G4 + r];
#pragma unroll
            for (int g = 0; g < 8; ++g) acc[g] += wv * xl[g][c];
        }
        float bi = b_ih[r];
#pragma unroll
        for (int g = 0; g < 8; ++g) xg[(size_t)(nb + g) * G4 + r] = acc[g] + bi;
    }
}

// MV + cell for one pow2 batch of G nodes, one 30-unit slice.
template <int G>
__device__ __forceinline__ void mv_cell(const float (&w)[75], int t, int slice,
                                        const int* __restrict__ nid_s,
                                        const float* __restrict__ xg,
                                        const float* __restrict__ b_hh,
                                        u16* __restrict__ hb16,
                                        float* __restrict__ c_buf,
                                        const float* __restrict__ ph,
                                        float* __restrict__ pr,
                                        const float* __restrict__ pcl) {
    if (t < 480) {
        float acc[G];
#pragma unroll
        for (int j = 0; j < G; ++j) acc[j] = 0.f;
        const int cb = (t / NROW) * 75;
#pragma unroll 5
        for (int i = 0; i < 75; ++i) {
            const float wv = w[i];
            const float* pp = &ph[(cb + i) * GMAX];
            if constexpr (G >= 4) {
#pragma unroll
                for (int j4 = 0; j4 < G; j4 += 4) {
                    f32x4 a = *(const f32x4*)&pp[j4];
                    acc[j4 + 0] = fmaf(wv, a[0], acc[j4 + 0]);
                    acc[j4 + 1] = fmaf(wv, a[1], acc[j4 + 1]);
                    acc[j4 + 2] = fmaf(wv, a[2], acc[j4 + 2]);
                    acc[j4 + 3] = fmaf(wv, a[3], acc[j4 + 3]);
                }
            } else {
#pragma unroll
                for (int j = 0; j < G; ++j) acc[j] = fmaf(wv, pp[j], acc[j]);
            }
        }
#pragma unroll
        for (int j = 0; j < G; ++j) pr[j * PRW + t] = acc[j];
    }
    __syncthreads();
    // cell: thread t < 15*G handles (node j, unit pair up)
    if (t < 15 * G) {
        const int j = t / 15, up = t - j * 15;
        const int ul0 = up * 2;
        const int n = nid_s[j];
        const int b = n >> 7, i = n & 127;
        const int u0 = slice * UPS + ul0;
        const float* pj = pr + j * PRW;
        const float* xgp = xg + (size_t)n * G4;
        float cv[2], hv[2];
#pragma unroll
        for (int un = 0; un < 2; ++un) {
            const int ul = ul0 + un, u = u0 + un;
            float gs[4];
#pragma unroll
            for (int g = 0; g < 4; ++g) {
                const int rr = g * UPS + ul;
                float sum = pj[rr] + pj[NROW + rr] + pj[2 * NROW + rr] + pj[3 * NROW + rr];
                gs[g] = sum + xgp[g * HH + u] + b_hh[g * HH + u];
            }
            const float pc = pcl[j * UPS + ul];
            cv[un] = sigm(gs[1]) * pc + sigm(gs[0]) * tanh_f(gs[2]);
            hv[un] = sigm(gs[3]) * tanh_f(cv[un]);
        }
        const size_t row = (size_t)(b * 129 + i + 1);
        union { float f[2]; u64 v; } cp; cp.f[0] = cv[0]; cp.f[1] = cv[1];
        A_ST((u64*)(c_buf + row * HH + u0), cp.v);
        u32 hp = (u32)f2bf(hv[0]) | ((u32)f2bf(hv[1]) << 16);
        A_ST((u32*)(hb16 + row * KP + u0), hp);
    }
}

// Dataflow scan: 10 slices x 20 reps = 200 blocks, normal launch, no queue.
// Block owns fixed node-id chunks; wave-0 ballot-sweep picks any ready nodes
// (done[parent]==NSLICE). h/c via relaxed agent-scope atomics (MALL-coherent).
__global__ __launch_bounds__(TPB, 2) void k_scan_slice(const int* __restrict__ parents,
                                                       const float* __restrict__ Wpack,
                                                       const float* __restrict__ xg,
                                                       const float* __restrict__ b_hh,
                                                       u16* __restrict__ hb16,
                                                       float* __restrict__ c_buf,
                                                       int* __restrict__ done) {
    __shared__ __align__(16) float ph[HH * GMAX];   // 19.2 KB parent h, [c][j]
    __shared__ float pr[GMAX * PRW];                // 31.0 KB MV partials, [j][t]
    __shared__ float pcl[UPS * GMAX];               // 1.9 KB parent c slice
    __shared__ int own_s[MAXOWN];
    __shared__ unsigned char proc_s[MAXOWN];
    __shared__ int nid_s[GMAX];
    __shared__ int par_s[GMAX];
    __shared__ int ksel_s[GMAX];
    __shared__ int gc_s, npend_s, cur_s;

    const int t = threadIdx.x;
    const int rep = blockIdx.x % NREP;
    const int slice = blockIdx.x / NREP;

    const int nch = (NCHUNK - 1 - rep) / NREP + 1;
    const int nown = nch * 16;
    for (int k = t; k < nown; k += TPB) {
        own_s[k] = (rep + (k >> 4) * NREP) * 16 + (k & 15);
        proc_s[k] = 0;
    }
    if (t == 0) npend_s = nown;

    // register-resident W slice (once per block, coalesced)
    float w[75];
    if (t < 480) {
        const float* wp = Wpack + (size_t)slice * 75 * 480 + t;
#pragma unroll
        for (int i = 0; i < 75; ++i) w[i] = wp[i * 480];
    }

    while (true) {
        __syncthreads();
        if (npend_s == 0) break;
        // wave-0 ballot sweep: select up to GMAX ready nodes anywhere in owned set
        if (t < 64) {
            int cur = 0;
            for (int base = 0; base < nown && cur < GMAX; base += 64) {
                const int k = base + t;
                int n = -1, p = -1;
                bool rdy = false;
                if (k < nown && !proc_s[k]) {
                    n = own_s[k];
                    p = parents[n];
                    rdy = (p < 0) || (A_LD(&done[(n & ~127) + p]) == NSLICE);
                }
                u64 mask = __ballot(rdy);
                if (rdy) {
                    int pos = cur + __popcll(mask & ((1ull << t) - 1));
                    if (pos < GMAX) {
                        nid_s[pos] = n;
                        par_s[pos] = p;
                        ksel_s[pos] = k;
                        proc_s[k] = 1;
                    }
                }
                cur += __popcll(mask);
            }
            if (t == 0) cur_s = (cur > GMAX) ? GMAX : cur;
        }
        __syncthreads();
        if (t == 0) {
            int c = cur_s;
            int gsel = 0;
            if (c > 0) { gsel = 1; while (gsel * 2 <= c) gsel *= 2; }
            for (int p2 = gsel; p2 < c; ++p2) proc_s[ksel_s[p2]] = 0;  // un-select
            npend_s -= gsel;
            gc_s = gsel;
        }
        __syncthreads();
        const int gc = gc_s;
        if (gc == 0) { __builtin_amdgcn_s_sleep(2); continue; }
        // stage parent h: u64 loads of 4xbf16, 4-wq groups per node for coalescing
        {
            const int tot = gc * 80;
            for (int e = t; e < tot; e += TPB) {
                const int wqlo = e & 3, rest = e >> 2;
                const int j = rest % gc, wq4 = rest / gc;
                const int wq = wq4 * 4 + wqlo;
                if (wq < 75) {
                    const int n = nid_s[j];
                    const u64* hrow = (const u64*)(hb16 +
                        (size_t)((n >> 7) * 129 + par_s[j] + 1) * KP);
                    u64 v = A_LD(&hrow[wq]);
                    const int c0 = wq * 4;
                    ph[(c0 + 0) * GMAX + j] = bf2f((u16)v);
                    ph[(c0 + 1) * GMAX + j] = bf2f((u16)(v >> 16));
                    ph[(c0 + 2) * GMAX + j] = bf2f((u16)(v >> 32));
                    ph[(c0 + 3) * GMAX + j] = bf2f((u16)(v >> 48));
                }
            }
        }
        // stage parent c slice (15 u64 per node)
        {
            const int tot = gc * 16;
            for (int e = t; e < tot; e += TPB) {
                const int wqlo = e & 3, rest = e >> 2;
                const int j = rest % gc, wq4 = rest / gc;
                const int wq = wq4 * 4 + wqlo;
                if (wq < 15) {
                    const int n = nid_s[j];
                    const u64* crow = (const u64*)(c_buf +
                        (size_t)((n >> 7) * 129 + par_s[j] + 1) * HH + slice * UPS);
                    u64 v = A_LD(&crow[wq]);
                    union { u64 v; float f[2]; } uu; uu.v = v;
                    pcl[j * UPS + wq * 2] = uu.f[0];
                    pcl[j * UPS + wq * 2 + 1] = uu.f[1];
                }
            }
        }
        __syncthreads();
        switch (gc) {
            case 16: mv_cell<16>(w, t, slice, nid_s, xg, b_hh, hb16, c_buf, ph, pr, pcl); break;
            case 8:  mv_cell<8>(w, t, slice, nid_s, xg, b_hh, hb16, c_buf, ph, pr, pcl); break;
            case 4:  mv_cell<4>(w, t, slice, nid_s, xg, b_hh, hb16, c_buf, ph, pr, pcl); break;
            case 2:  mv_cell<2>(w, t, slice, nid_s, xg, b_hh, hb16, c_buf, ph, pr, pcl); break;
            default: mv_cell<1>(w, t, slice, nid_s, xg, b_hh, hb16, c_buf, ph, pr, pcl); break;
        }
        // barrier drains all threads' h/c atomic stores before done adds
        __syncthreads();
        if (t < gc) A_ADD(&done[nid_s[t]], 1);
    }
}

// cast W_out -> bf16 [32000][320] (zero-padded K)
__global__ void k_cast_B(const float* __restrict__ W_out, u16* __restrict__ Bm) {
    for (int e = blockIdx.x * blockDim.x + threadIdx.x; e < NV * KP;
         e += gridDim.x * blockDim.x) {
        int v = e / KP, k = e - v * KP;
        float x = (k < HH) ? W_out[v * HH + k] : 0.f;
        Bm[e] = f2bf(x);
    }
}

// logits[4096][32000] = A(bf16, from hb16) @ B(bf16)^T + b_out, fp32 accum.
// 1D grid 8000, XCD-swizzled: each XCD owns a contiguous nblk range -> B read ~once.
__global__ __launch_bounds__(256) void k_gemm(const u16* __restrict__ hb16,
                                              const u16* __restrict__ Bbf,
                                              const float* __restrict__ b_out,
                                              float* __restrict__ out) {
    __shared__ __align__(16) u16 As[128 * 40];
    __shared__ __align__(16) u16 Bs[128 * 40];
    const int tid = threadIdx.x;
    const int lane = tid & 63, wv = tid >> 6;
    const int wm = wv >> 1, wn = wv & 1;
    const int bid = blockIdx.x;                  // 8000 = 32 mblk x 250 nblk
    const int newbid = (bid & 7) * 1000 + (bid >> 3);
    const int mblk = newbid & 31, nblk = newbid >> 5;
    const u16* Ag = hb16 + ((size_t)mblk * 129 + 1) * KP;
    const u16* Bg = Bbf + (size_t)nblk * 128 * KP;
    f32x4 acc[4][4] = {};
    const int lrow = lane & 15, lseg = lane >> 4;
    for (int kk = 0; kk < KP; kk += 32) {
#pragma unroll
        for (int q = 0; q < 2; ++q) {
            int s = tid + q * 256;
            int r = s >> 2, seg = s & 3;
            *(uint4*)&As[r * 40 + seg * 8] = *(const uint4*)&Ag[r * KP + kk + seg * 8];
            *(uint4*)&Bs[r * 40 + seg * 8] = *(const uint4*)&Bg[r * KP + kk + seg * 8];
        }
        __syncthreads();
        short8 av[4], bv[4];
#pragma unroll
        for (int i = 0; i < 4; ++i) {
            av[i] = *(const short8*)&As[(wm * 64 + i * 16 + lrow) * 40 + lseg * 8];
            bv[i] = *(const short8*)&Bs[(wn * 64 + i * 16 + lrow) * 40 + lseg * 8];
        }
#pragma unroll
        for (int i = 0; i < 4; ++i)
#pragma unroll
            for (int j = 0; j < 4; ++j)
                acc[i][j] = __builtin_amdgcn_mfma_f32_16x16x32_bf16(av[i], bv[j], acc[i][j],
                                                                    0, 0, 0);
        __syncthreads();
    }
#pragma unroll
    for (int j = 0; j < 4; ++j) {
        int col = nblk * 128 + wn * 64 + j * 16 + lrow;
        float bo = b_out[col];
#pragma unroll
        for (int i = 0; i < 4; ++i) {
            int row0 = mblk * 128 + wm * 64 + i * 16 + lseg * 4;
#pragma unroll
            for (int q = 0; q < 4; ++q) {
                out[(size_t)(row0 + q) * NV + col] = acc[i][j][q] + bo;
            }
        }
    }
}

extern "C" void kernel_launch(void* const* d_in, const int* in_sizes, int n_in,
                              void* d_out, int out_size, void* d_ws, size_t ws_size,
                              hipStream_t stream) {
    const float* root_hidden = (const float*)d_in[0];
    const int* relations = (const int*)d_in[1];
    const int* prev_words = (const int*)d_in[2];
    const int* parents = (const int*)d_in[3];
    const float* emb = (const float*)d_in[4];
    const float* rel_emb = (const float*)d_in[5];
    const float* W_ih = (const float*)d_in[6];
    const float* W_hh = (const float*)d_in[7];
    const float* b_ih = (const float*)d_in[8];
    const float* b_hh = (const float*)d_in[9];
    const float* W_out = (const float*)d_in[10];
    const float* b_out = (const float*)d_in[11];
    float* out = (float*)d_out;

    float* WihT = (float*)d_ws;                  // 420000 f32
    float* Wpack = WihT + 420000;                // 360000 f32
    float* xg = Wpack + 360000;                  // 4915200 f32
    float* c_buf = xg + 4915200;                 // 1238400 f32
    u16* hb16 = (u16*)(c_buf + 1238400);         // 32*129*320 = 1320960 u16
    u16* Bbf = hb16 + 1320960;                   // 10240000 u16
    int* done = (int*)(Bbf + 10240000);          // 4096 i32

    k_init<<<128, 256, 0, stream>>>(root_hidden, hb16, c_buf, done);
    k_pack<<<2048, 256, 0, stream>>>(W_ih, W_hh, WihT, Wpack);
    k_xg<<<NB * NN / 8, 256, 0, stream>>>(relations, prev_words, rel_emb, emb, WihT, b_ih, xg);

    k_scan_slice<<<dim3(NSLICE * NREP), dim3(TPB), 0, stream>>>(
        parents, Wpack, xg, b_hh, hb16, c_buf, done);

    k_cast_B<<<4096, 256, 0, stream>>>(W_out, Bbf);
    k_gemm<<<dim3(8000), 256, 0, stream>>>(hb16, Bbf, b_out, out);
}

// Round 9
// 658.378 us; speedup vs baseline: 1.2063x; 1.2063x over previous
//
#include <hip/hip_runtime.h>
#include <hip/hip_bf16.h>

typedef unsigned short u16;
typedef unsigned int u32;
typedef unsigned long long u64;
typedef __attribute__((ext_vector_type(8))) short short8;
typedef __attribute__((ext_vector_type(4))) float f32x4;

#define NB 32      // trees
#define NN 128     // nodes per tree
#define HH 300     // hidden
#define G4 1200    // 4*H
#define NV 32000   // vocab
#define INW 350    // RD+E
#define KP 320     // padded K for MFMA; hb16 row stride

// scan decomposition: 32 trees x 10 slice-blocks, level-synchronous per tree
#define NSLICE 10   // 10 slices x 30 units
#define UPS 30      // hidden units per slice -> 120 gate rows
#define NROW 120
#define TPB 512     // 480 active MV lanes (120 rows x 4 col-chunks of 75)
#define GMAX 16     // max nodes per MV pass
#define PRW 484     // padded pr row stride

#define A_LD(p)     __hip_atomic_load((p), __ATOMIC_RELAXED, __HIP_MEMORY_SCOPE_AGENT)
#define A_ST(p, v)  __hip_atomic_store((p), (v), __ATOMIC_RELAXED, __HIP_MEMORY_SCOPE_AGENT)
#define A_ADD(p, v) __hip_atomic_fetch_add((p), (v), __ATOMIC_RELAXED, __HIP_MEMORY_SCOPE_AGENT)

__device__ __forceinline__ float sigm(float x) { return 1.f / (1.f + __expf(-x)); }
__device__ __forceinline__ float tanh_f(float x) {
    float e = __expf(2.f * x);
    return 1.f - 2.f / (e + 1.f);
}
__device__ __forceinline__ float bf2f(u16 v) {
    u32 u = ((u32)v) << 16;
    return __uint_as_float(u);
}
__device__ __forceinline__ u16 f2bf(float f) {
    __hip_bfloat16 b = __float2bfloat16(f);
    return *reinterpret_cast<u16*>(&b);
}

// hb16: [B][129][320] bf16, slot 0 = root h; lvl_done zeroed
__global__ void k_init(const float* __restrict__ rh, u16* __restrict__ hb16,
                       int* __restrict__ lvl_done) {
    const int stride = gridDim.x * blockDim.x;
    const int idx = blockIdx.x * blockDim.x + threadIdx.x;
    for (int e = idx; e < NB * 129 * 20; e += stride) {
        int row = e / 20, c = 300 + (e - row * 20);
        hb16[(size_t)row * KP + c] = 0;
    }
    for (int e = idx; e < NB * HH; e += stride) {
        int b = e / HH, u = e - b * HH;
        hb16[(size_t)(b * 129) * KP + u] = f2bf(rh[e]);
    }
    for (int e = idx; e < NB * NN; e += stride) lvl_done[e] = 0;
}

// WihT [350][1200]; Wpack[slice][i<75][t<480] = W_hh[row(s,t)][(t/120)*75+i]
// row(s,t) = 300*(rl/30) + 30*s + rl%30, rl = t%120
__global__ void k_pack(const float* __restrict__ W_ih, const float* __restrict__ W_hh,
                       float* __restrict__ WihT, float* __restrict__ Wpack) {
    const int tot = INW * G4 + NSLICE * 75 * 480;
    for (int n = blockIdx.x * blockDim.x + threadIdx.x; n < tot; n += gridDim.x * blockDim.x) {
        if (n < INW * G4) {
            int c = n / G4, r = n - c * G4;
            WihT[n] = W_ih[r * INW + c];
        } else {
            int m = n - INW * G4;
            int s = m / (75 * 480);
            int rem = m - s * (75 * 480);
            int i = rem / 480, t = rem - i * 480;
            int rl = t % NROW, cc = t / NROW;
            int row = 300 * (rl / UPS) + UPS * s + (rl % UPS);
            int col = cc * 75 + i;
            Wpack[m] = W_hh[row * HH + col];
        }
    }
}

// xg[node][1200] = concat(rel_emb[rel], emb[word]) @ W_ih^T + b_ih
__global__ __launch_bounds__(256) void k_xg(const int* __restrict__ relations,
                                            const int* __restrict__ prev_words,
                                            const float* __restrict__ rel_emb,
                                            const float* __restrict__ emb,
                                            const float* __restrict__ WihT,
                                            const float* __restrict__ b_ih,
                                            float* __restrict__ xg) {
    __shared__ float xl[8][INW];
    __shared__ int rid[8], wid[8];
    const int tid = threadIdx.x;
    const int nb = blockIdx.x * 8;
    if (tid < 8) { rid[tid] = relations[nb + tid]; wid[tid] = prev_words[nb + tid]; }
    __syncthreads();
    for (int idx = tid; idx < 8 * INW; idx += 256) {
        int g = idx / INW, c = idx - g * INW;
        xl[g][c] = (c < 50) ? rel_emb[rid[g] * 50 + c] : emb[wid[g] * HH + (c - 50)];
    }
    __syncthreads();
    for (int k = 0; k < 5; ++k) {
        int r = k * 256 + tid;
        if (r >= G4) break;
        float acc[8] = {0.f, 0.f, 0.f, 0.f, 0.f, 0.f, 0.f, 0.f};
        for (int c = 0; c < INW; ++c) {
            float wv = WihT[(size_t)c * G4 + r];
#pragma unroll
            for (int g = 0; g < 8; ++g) acc[g] += wv * xl[g][c];
        }
        float bi = b_ih[r];
#pragma unroll
        for (int g = 0; g < 8; ++g) xg[(size_t)(nb + g) * G4 + r] = acc[g] + bi;
    }
}

// per-tree level schedule: lvl_nodes[b][pos], lvl_cnt[b][l], lvl_start[b][l], nlev[b]
__global__ void k_prep(const int* __restrict__ parents, int* __restrict__ lvl_nodes,
                       int* __restrict__ lvl_cnt, int* __restrict__ lvl_start,
                       int* __restrict__ nlev) {
    __shared__ int dep[NB][NN];
    __shared__ int cnt[NB][NN];
    __shared__ int st[NB][NN];
    const int t = threadIdx.x;
    if (t < NB) {
        for (int l = 0; l < NN; ++l) cnt[t][l] = 0;
        int md = 0;
        for (int i = 0; i < NN; ++i) {
            int p = parents[t * NN + i];
            int d = (p < 0) ? 0 : dep[t][p] + 1;
            dep[t][i] = d;
            cnt[t][d]++;
            md = max(md, d);
        }
        nlev[t] = md + 1;
        int run = 0;
        for (int l = 0; l < NN; ++l) {
            st[t][l] = run;
            lvl_start[t * NN + l] = run;
            lvl_cnt[t * NN + l] = cnt[t][l];
            run += cnt[t][l];
        }
        for (int i = 0; i < NN; ++i) {
            int d = dep[t][i];
            lvl_nodes[t * NN + st[t][d]] = i;
            st[t][d]++;
        }
    }
}

// MV + cell for one pow2 batch of G nodes. W fully register-resident (full unroll);
// c slice lives in LDS (slice-local); h published to hb16 via agent-scope atomics.
template <int G>
__device__ __forceinline__ void mv_cell(const float (&w)[75], int t, int s, int b,
                                        const int* __restrict__ nid_s,
                                        const int* __restrict__ par_s,
                                        const float* __restrict__ xg,
                                        const float* __restrict__ b_hh,
                                        u16* __restrict__ hb16,
                                        const float* __restrict__ ph,
                                        float* __restrict__ pr,
                                        float* __restrict__ c_lds) {
    if (t < 480) {
        float acc[G];
#pragma unroll
        for (int j = 0; j < G; ++j) acc[j] = 0.f;
        const int cb = (t / NROW) * 75;
#pragma unroll
        for (int i = 0; i < 75; ++i) {
            const float wv = w[i];
            const float* pp = &ph[(cb + i) * GMAX];
            if constexpr (G >= 4) {
#pragma unroll
                for (int j4 = 0; j4 < G; j4 += 4) {
                    f32x4 a = *(const f32x4*)&pp[j4];
                    acc[j4 + 0] = fmaf(wv, a[0], acc[j4 + 0]);
                    acc[j4 + 1] = fmaf(wv, a[1], acc[j4 + 1]);
                    acc[j4 + 2] = fmaf(wv, a[2], acc[j4 + 2]);
                    acc[j4 + 3] = fmaf(wv, a[3], acc[j4 + 3]);
                }
            } else {
#pragma unroll
                for (int j = 0; j < G; ++j) acc[j] = fmaf(wv, pp[j], acc[j]);
            }
        }
#pragma unroll
        for (int j = 0; j < G; ++j) pr[j * PRW + t] = acc[j];
    }
    __syncthreads();
    // cell: thread t < 15*G handles (node j, unit pair up)
    if (t < 15 * G) {
        const int j = t / 15, up = t - j * 15;
        const int ul0 = up * 2;
        const int i = nid_s[j];
        const int par = par_s[j];
        const int u0 = s * UPS + ul0;
        const float* pj = pr + j * PRW;
        const float* xgp = xg + (size_t)(b * NN + i) * G4;
        float cv[2], hv[2];
#pragma unroll
        for (int un = 0; un < 2; ++un) {
            const int ul = ul0 + un, u = u0 + un;
            float gs[4];
#pragma unroll
            for (int g = 0; g < 4; ++g) {
                const int rr = g * UPS + ul;
                float sum = pj[rr] + pj[NROW + rr] + pj[2 * NROW + rr] + pj[3 * NROW + rr];
                gs[g] = sum + xgp[g * HH + u] + b_hh[g * HH + u];
            }
            const float pc = c_lds[(par + 1) * UPS + ul];
            cv[un] = sigm(gs[1]) * pc + sigm(gs[0]) * tanh_f(gs[2]);
            hv[un] = sigm(gs[3]) * tanh_f(cv[un]);
        }
        c_lds[(i + 1) * UPS + ul0] = cv[0];
        c_lds[(i + 1) * UPS + ul0 + 1] = cv[1];
        u32 hp = (u32)f2bf(hv[0]) | ((u32)f2bf(hv[1]) << 16);
        A_ST((u32*)(hb16 + (size_t)(b * 129 + i + 1) * KP + u0), hp);
    }
}

// Level-synchronous per-tree scan: block (b,s); group = 10 contiguous block ids.
// One rendezvous per level via lvl_done[b][l] counter (agent-scope atomics, the
// R6-8-proven protocol). No selection logic; schedule precomputed by k_prep.
// Deadlock-free: deps only within a group; group ids contiguous -> dispatch
// frontier always completes whole groups before partial ones.
__global__ __launch_bounds__(TPB, 2) void k_scan(const int* __restrict__ parents,
                                                 const float* __restrict__ Wpack,
                                                 const float* __restrict__ xg,
                                                 const float* __restrict__ b_hh,
                                                 const float* __restrict__ rh,
                                                 u16* __restrict__ hb16,
                                                 const int* __restrict__ lvl_nodes,
                                                 const int* __restrict__ lvl_cnt,
                                                 const int* __restrict__ lvl_start,
                                                 const int* __restrict__ nlev,
                                                 int* __restrict__ lvl_done) {
    __shared__ __align__(16) float ph[HH * GMAX];   // 19.2 KB parent h, [c][j]
    __shared__ float pr[GMAX * PRW];                // 31.0 KB MV partials, [j][t]
    __shared__ float c_lds[129 * UPS];              // 15.5 KB slice-local c
    __shared__ int nid_s[GMAX], par_s[GMAX];

    const int t = threadIdx.x;
    const int b = blockIdx.x / NSLICE;   // tree
    const int s = blockIdx.x % NSLICE;   // slice

    // W slice: truly register-resident (FULL unroll -> static indices)
    float w[75];
    if (t < 480) {
        const float* wp = Wpack + (size_t)s * 75 * 480 + t;
#pragma unroll
        for (int i = 0; i < 75; ++i) w[i] = wp[i * 480];
    }
    // root c for this slice
    if (t < UPS) c_lds[t] = rh[b * HH + s * UPS + t];

    const int nl = nlev[b];
    for (int l = 0; l < nl; ++l) {
        const int cnt = lvl_cnt[b * NN + l];
        const int start = lvl_start[b * NN + l];
        int off = 0;
        while (off < cnt) {
            const int rem = cnt - off;
            const int g = rem >= 16 ? 16 : rem >= 8 ? 8 : rem >= 4 ? 4 : rem >= 2 ? 2 : 1;
            if (t < g) {
                int i = lvl_nodes[b * NN + start + off + t];
                nid_s[t] = i;
                par_s[t] = parents[b * NN + i];
            }
            __syncthreads();
            // stage parent h: u64 loads of 4xbf16 (parents are from earlier levels)
            const int tot = g * 80;
            for (int e = t; e < tot; e += TPB) {
                const int wqlo = e & 3, rest = e >> 2;
                const int j = rest % g, wq4 = rest / g;
                const int wq = wq4 * 4 + wqlo;
                if (wq < 75) {
                    const u64* hrow = (const u64*)(hb16 +
                        (size_t)(b * 129 + par_s[j] + 1) * KP);
                    u64 v = A_LD(&hrow[wq]);
                    const int c0 = wq * 4;
                    ph[(c0 + 0) * GMAX + j] = bf2f((u16)v);
                    ph[(c0 + 1) * GMAX + j] = bf2f((u16)(v >> 16));
                    ph[(c0 + 2) * GMAX + j] = bf2f((u16)(v >> 32));
                    ph[(c0 + 3) * GMAX + j] = bf2f((u16)(v >> 48));
                }
            }
            __syncthreads();
            switch (g) {
                case 16: mv_cell<16>(w, t, s, b, nid_s, par_s, xg, b_hh, hb16, ph, pr, c_lds); break;
                case 8:  mv_cell<8>(w, t, s, b, nid_s, par_s, xg, b_hh, hb16, ph, pr, c_lds); break;
                case 4:  mv_cell<4>(w, t, s, b, nid_s, par_s, xg, b_hh, hb16, ph, pr, c_lds); break;
                case 2:  mv_cell<2>(w, t, s, b, nid_s, par_s, xg, b_hh, hb16, ph, pr, c_lds); break;
                default: mv_cell<1>(w, t, s, b, nid_s, par_s, xg, b_hh, hb16, ph, pr, c_lds); break;
            }
            __syncthreads();  // drains h publishes (vmcnt0) + LDS reuse safety
            off += g;
        }
        if (l + 1 < nl) {  // rendezvous: all 10 slice-blocks of tree b finish level l
            if (t == 0) {
                int* dp = &lvl_done[b * NN + l];
                const int old = A_ADD(dp, 1);
                if (old != NSLICE - 1) {
                    while (A_LD(dp) < NSLICE) __builtin_amdgcn_s_sleep(1);
                }
            }
            __syncthreads();
        }
    }
}

// cast W_out -> bf16 [32000][320] (zero-padded K)
__global__ void k_cast_B(const float* __restrict__ W_out, u16* __restrict__ Bm) {
    for (int e = blockIdx.x * blockDim.x + threadIdx.x; e < NV * KP;
         e += gridDim.x * blockDim.x) {
        int v = e / KP, k = e - v * KP;
        float x = (k < HH) ? W_out[v * HH + k] : 0.f;
        Bm[e] = f2bf(x);
    }
}

// logits[4096][32000] = A(bf16, from hb16) @ B(bf16)^T + b_out, fp32 accum.
// 1D grid 8000, XCD-swizzled: each XCD owns a contiguous nblk range.
__global__ __launch_bounds__(256) void k_gemm(const u16* __restrict__ hb16,
                                              const u16* __restrict__ Bbf,
                                              const float* __restrict__ b_out,
                                              float* __restrict__ out) {
    __shared__ __align__(16) u16 As[128 * 40];
    __shared__ __align__(16) u16 Bs[128 * 40];
    const int tid = threadIdx.x;
    const int lane = tid & 63, wv = tid >> 6;
    const int wm = wv >> 1, wn = wv & 1;
    const int bid = blockIdx.x;                  // 8000 = 32 mblk x 250 nblk
    const int newbid = (bid & 7) * 1000 + (bid >> 3);
    const int mblk = newbid & 31, nblk = newbid >> 5;
    const u16* Ag = hb16 + ((size_t)mblk * 129 + 1) * KP;
    const u16* Bg = Bbf + (size_t)nblk * 128 * KP;
    f32x4 acc[4][4] = {};
    const int lrow = lane & 15, lseg = lane >> 4;
    for (int kk = 0; kk < KP; kk += 32) {
#pragma unroll
        for (int q = 0; q < 2; ++q) {
            int s = tid + q * 256;
            int r = s >> 2, seg = s & 3;
            *(uint4*)&As[r * 40 + seg * 8] = *(const uint4*)&Ag[r * KP + kk + seg * 8];
            *(uint4*)&Bs[r * 40 + seg * 8] = *(const uint4*)&Bg[r * KP + kk + seg * 8];
        }
        __syncthreads();
        short8 av[4], bv[4];
#pragma unroll
        for (int i = 0; i < 4; ++i) {
            av[i] = *(const short8*)&As[(wm * 64 + i * 16 + lrow) * 40 + lseg * 8];
            bv[i] = *(const short8*)&Bs[(wn * 64 + i * 16 + lrow) * 40 + lseg * 8];
        }
#pragma unroll
        for (int i = 0; i < 4; ++i)
#pragma unroll
            for (int j = 0; j < 4; ++j)
                acc[i][j] = __builtin_amdgcn_mfma_f32_16x16x32_bf16(av[i], bv[j], acc[i][j],
                                                                    0, 0, 0);
        __syncthreads();
    }
#pragma unroll
    for (int j = 0; j < 4; ++j) {
        int col = nblk * 128 + wn * 64 + j * 16 + lrow;
        float bo = b_out[col];
#pragma unroll
        for (int i = 0; i < 4; ++i) {
            int row0 = mblk * 128 + wm * 64 + i * 16 + lseg * 4;
#pragma unroll
            for (int q = 0; q < 4; ++q) {
                out[(size_t)(row0 + q) * NV + col] = acc[i][j][q] + bo;
            }
        }
    }
}

extern "C" void kernel_launch(void* const* d_in, const int* in_sizes, int n_in,
                              void* d_out, int out_size, void* d_ws, size_t ws_size,
                              hipStream_t stream) {
    const float* root_hidden = (const float*)d_in[0];
    const int* relations = (const int*)d_in[1];
    const int* prev_words = (const int*)d_in[2];
    const int* parents = (const int*)d_in[3];
    const float* emb = (const float*)d_in[4];
    const float* rel_emb = (const float*)d_in[5];
    const float* W_ih = (const float*)d_in[6];
    const float* W_hh = (const float*)d_in[7];
    const float* b_ih = (const float*)d_in[8];
    const float* b_hh = (const float*)d_in[9];
    const float* W_out = (const float*)d_in[10];
    const float* b_out = (const float*)d_in[11];
    float* out = (float*)d_out;

    float* WihT = (float*)d_ws;                  // 420000 f32
    float* Wpack = WihT + 420000;                // 360000 f32
    float* xg = Wpack + 360000;                  // 4915200 f32
    u16* hb16 = (u16*)(xg + 4915200);            // 32*129*320 = 1320960 u16
    u16* Bbf = hb16 + 1320960;                   // 10240000 u16
    int* lvl_nodes = (int*)(Bbf + 10240000);     // 4096 i32
    int* lvl_cnt = lvl_nodes + 4096;             // 4096 i32
    int* lvl_start = lvl_cnt + 4096;             // 4096 i32
    int* nlev = lvl_start + 4096;                // 32 i32 (+pad)
    int* lvl_done = nlev + 64;                   // 4096 i32

    k_init<<<128, 256, 0, stream>>>(root_hidden, hb16, lvl_done);
    k_pack<<<2048, 256, 0, stream>>>(W_ih, W_hh, WihT, Wpack);
    k_xg<<<NB * NN / 8, 256, 0, stream>>>(relations, prev_words, rel_emb, emb, WihT, b_ih, xg);
    k_prep<<<1, 64, 0, stream>>>(parents, lvl_nodes, lvl_cnt, lvl_start, nlev);

    k_scan<<<dim3(NB * NSLICE), dim3(TPB), 0, stream>>>(
        parents, Wpack, xg, b_hh, root_hidden, hb16,
        lvl_nodes, lvl_cnt, lvl_start, nlev, lvl_done);

    k_cast_B<<<4096, 256, 0, stream>>>(W_out, Bbf);
    k_gemm<<<dim3(8000), 256, 0, stream>>>(hb16, Bbf, b_out, out);
}